// Round 1
// baseline (601.754 us; speedup 1.0000x reference)
//
#include <hip/hip_runtime.h>
#include <hip/hip_bf16.h>
#include <stdint.h>

#define NEG_BIG (-1e24f)

typedef __attribute__((ext_vector_type(8))) short bf16x8;
typedef __attribute__((ext_vector_type(4))) float f32x4;

#define AS1 __attribute__((address_space(1)))
#define AS3 __attribute__((address_space(3)))

__device__ __forceinline__ void gload_lds16(const void* g, void* l) {
    __builtin_amdgcn_global_load_lds((AS1 unsigned*)g, (AS3 unsigned*)l, 16, 0, 0);
}

__device__ __forceinline__ unsigned short f2bf(float f) {
    union { float f; unsigned u; } v; v.f = f;
    return (unsigned short)((v.u + 0x7FFFu + ((v.u >> 16) & 1u)) >> 16);
}

// ---------------------------------------------------------------------------
// K0: detect padding_mask storage dtype from its bit patterns.
// flag: 0 = int32 {0,1}, 1 = uint8 bytes, 2 = float32 {0.0,1.0}
__global__ void detect_mask_kernel(const unsigned* pm, int* flag) {
    __shared__ int notI, notF;
    if (threadIdx.x == 0) { notI = 0; notF = 0; }
    __syncthreads();
    int li = 0, lf = 0;
    for (int i = threadIdx.x; i < 8192; i += 256) {   // 8192 words is safe for all 3 layouts
        unsigned v = pm[i];
        if (v > 1u) li = 1;
        if (v != 0u && v != 0x3F800000u) lf = 1;
    }
    if (li) atomicOr(&notI, 1);
    if (lf) atomicOr(&notF, 1);
    __syncthreads();
    if (threadIdx.x == 0) *flag = notI ? (notF ? 1 : 2) : 0;
}

// ---------------------------------------------------------------------------
// K1: per 64-row tile: q = x@Wq+bq, k = x@Wk+bk (masked to -1e24), x -> bf16.
// All in exact fp32 (the -1e24 score comparisons are threshold-sensitive).
__global__ __launch_bounds__(256, 2)
void qk_conv_kernel(const float* __restrict__ x,
                    const float* __restrict__ Wq, const float* __restrict__ bq,
                    const float* __restrict__ Wk, const float* __restrict__ bk,
                    const void* __restrict__ pm, const int* __restrict__ pmflag,
                    unsigned short* __restrict__ xbf,
                    float* __restrict__ qo, float* __restrict__ ko) {
    __shared__ float sbuf[8448];  // phase A: xs[col 0..127][row 0..63] stride 65; phase B: reduce
    const int tid = threadIdx.x;
    const int r0 = blockIdx.x * 64;
    const int row = tid & 63;
    const int sub = tid >> 6;     // wave id: which 32-d slice this thread accumulates
    float qp[16], kp[16];
#pragma unroll
    for (int j = 0; j < 16; j++) { qp[j] = 0.f; kp[j] = 0.f; }

    for (int c0 = 0; c0 < 1024; c0 += 128) {
#pragma unroll
        for (int it = 0; it < 8; it++) {
            int idx = it * 1024 + tid * 4;
            int srow = idx >> 7;
            int scol = idx & 127;
            const float4 xv = *(const float4*)(x + (size_t)(r0 + srow) * 1024 + c0 + scol);
            sbuf[(scol + 0) * 65 + srow] = xv.x;
            sbuf[(scol + 1) * 65 + srow] = xv.y;
            sbuf[(scol + 2) * 65 + srow] = xv.z;
            sbuf[(scol + 3) * 65 + srow] = xv.w;
            uint2 pk;
            pk.x = (unsigned)f2bf(xv.x) | ((unsigned)f2bf(xv.y) << 16);
            pk.y = (unsigned)f2bf(xv.z) | ((unsigned)f2bf(xv.w) << 16);
            *(uint2*)(xbf + (size_t)(r0 + srow) * 1024 + c0 + scol) = pk;
        }
        __syncthreads();
        const int base = sub * 32;
#pragma unroll 4
        for (int i = 0; i < 32; i++) {
            int d = c0 + base + i;
            int du = __builtin_amdgcn_readfirstlane(d);  // wave-uniform -> s_load weights
            const float* wq = Wq + du * 16;
            const float* wk = Wk + du * 16;
            float xv = sbuf[(base + i) * 65 + row];
#pragma unroll
            for (int j = 0; j < 16; j++) qp[j] = fmaf(xv, wq[j], qp[j]);
#pragma unroll
            for (int j = 0; j < 16; j++) kp[j] = fmaf(xv, wk[j], kp[j]);
        }
        __syncthreads();
    }
    // reduce 4 partial slices per row through LDS (stride 33 to avoid pow2 banks)
#pragma unroll
    for (int j = 0; j < 16; j++) {
        sbuf[(sub * 64 + row) * 33 + j] = qp[j];
        sbuf[(sub * 64 + row) * 33 + 16 + j] = kp[j];
    }
    __syncthreads();
    const int flag = *pmflag;
#pragma unroll
    for (int jj = 0; jj < 4; jj++) {
        int qidx = tid * 4 + jj;
        int orow = qidx >> 4;
        int oj = qidx & 15;
        float qs = sbuf[(0 * 64 + orow) * 33 + oj] + sbuf[(1 * 64 + orow) * 33 + oj]
                 + sbuf[(2 * 64 + orow) * 33 + oj] + sbuf[(3 * 64 + orow) * 33 + oj] + bq[oj];
        float ks = sbuf[(0 * 64 + orow) * 33 + 16 + oj] + sbuf[(1 * 64 + orow) * 33 + 16 + oj]
                 + sbuf[(2 * 64 + orow) * 33 + 16 + oj] + sbuf[(3 * 64 + orow) * 33 + 16 + oj] + bk[oj];
        int gr = r0 + orow;
        bool masked;
        if (flag == 1) masked = ((const unsigned char*)pm)[gr] != 0;
        else           masked = ((const unsigned*)pm)[gr] != 0;
        if (masked) ks = NEG_BIG;
        qo[(size_t)gr * 16 + oj] = qs;
        ko[(size_t)gr * 16 + oj] = ks;
    }
}

// ---------------------------------------------------------------------------
// K2: WvT[n][k] = bf16(Wv[k][n])  (B-operand layout for MFMA GEMM)
__global__ void wvt_kernel(const float* __restrict__ Wv, unsigned short* __restrict__ WvT) {
    __shared__ float tile[32][33];
    const int k0 = blockIdx.x * 32, n0 = blockIdx.y * 32;
    const int tid = threadIdx.x;
#pragma unroll
    for (int i = 0; i < 4; i++) {
        int idx = i * 256 + tid;
        int r = idx >> 5, c = idx & 31;
        tile[r][c] = Wv[(size_t)(k0 + r) * 1024 + n0 + c];
    }
    __syncthreads();
#pragma unroll
    for (int i = 0; i < 4; i++) {
        int idx = i * 256 + tid;
        int r = idx >> 5, c = idx & 31;
        WvT[(size_t)(n0 + r) * 1024 + k0 + c] = f2bf(tile[c][r]);
    }
}

// ---------------------------------------------------------------------------
// K3: v[m][n] = bf16( xbf[m][:] @ WvT[n][:] + bv[n] ); m97-style 128x128x32
__global__ __launch_bounds__(256, 2)
void vgemm_kernel(const unsigned short* __restrict__ A,   // [32768][1024] bf16
                  const unsigned short* __restrict__ Bt,  // [1024][1024] bf16 (n-major)
                  const float* __restrict__ bias,
                  unsigned short* __restrict__ C) {       // [32768][1024] bf16
    __shared__ unsigned short As[128 * 32];
    __shared__ unsigned short Bs[128 * 32];
    const int tid = threadIdx.x;
    const int m0 = blockIdx.x * 128;
    const int n0 = blockIdx.y * 128;
    const int lane = tid & 63;
    const int wave = tid >> 6;
    const int wm = (wave & 1) * 64;
    const int wn = (wave >> 1) * 64;
    const int l15 = lane & 15;
    const int quad = lane >> 4;
    const int arow = tid >> 2;
    const int acol = (tid & 3) * 8;
    f32x4 acc[4][4];
#pragma unroll
    for (int i = 0; i < 4; i++)
#pragma unroll
        for (int j = 0; j < 4; j++)
#pragma unroll
            for (int r = 0; r < 4; r++) acc[i][j][r] = 0.f;

    for (int k0 = 0; k0 < 1024; k0 += 32) {
        gload_lds16(A + (size_t)(m0 + arow) * 1024 + k0 + acol, As + tid * 8);
        gload_lds16(A + (size_t)(m0 + 64 + arow) * 1024 + k0 + acol, As + 2048 + tid * 8);
        gload_lds16(Bt + (size_t)(n0 + arow) * 1024 + k0 + acol, Bs + tid * 8);
        gload_lds16(Bt + (size_t)(n0 + 64 + arow) * 1024 + k0 + acol, Bs + 2048 + tid * 8);
        __syncthreads();
        bf16x8 af[4], bfr[4];
#pragma unroll
        for (int i = 0; i < 4; i++) {
            af[i]  = *(const bf16x8*)(As + (wm + i * 16 + l15) * 32 + quad * 8);
            bfr[i] = *(const bf16x8*)(Bs + (wn + i * 16 + l15) * 32 + quad * 8);
        }
#pragma unroll
        for (int i = 0; i < 4; i++)
#pragma unroll
            for (int j = 0; j < 4; j++)
                acc[i][j] = __builtin_amdgcn_mfma_f32_16x16x32_bf16(af[i], bfr[j], acc[i][j], 0, 0, 0);
        __syncthreads();
    }
#pragma unroll
    for (int i = 0; i < 4; i++) {
        const int mrow = m0 + wm + i * 16 + quad * 4;
#pragma unroll
        for (int j = 0; j < 4; j++) {
            const int ncol = n0 + wn + j * 16 + l15;
            const float bb = bias[ncol];
#pragma unroll
            for (int r = 0; r < 4; r++)
                C[(size_t)(mrow + r) * 1024 + ncol] = f2bf(acc[i][j][r] + bb);
        }
    }
}

// ---------------------------------------------------------------------------
// K4: vT[b][e][s] = v[b][s][e]
__global__ void transpose_v_kernel(const unsigned short* __restrict__ v,
                                   unsigned short* __restrict__ vT) {
    __shared__ unsigned short t[64][66];
    const int tid = threadIdx.x;
    const int s0 = blockIdx.x * 64, e0 = blockIdx.y * 64, b = blockIdx.z;
    const unsigned short* vb = v + (size_t)b * 512 * 1024;
    unsigned short* vtb = vT + (size_t)b * 1024 * 512;
#pragma unroll
    for (int i = 0; i < 8; i++) {
        int li = i * 256 + tid;
        int r = li >> 5, c2 = (li & 31) * 2;
        unsigned val = *(const unsigned*)(vb + (size_t)(s0 + r) * 1024 + e0 + c2);
        t[r][c2] = (unsigned short)(val & 0xFFFFu);
        t[r][c2 + 1] = (unsigned short)(val >> 16);
    }
    __syncthreads();
#pragma unroll
    for (int i = 0; i < 8; i++) {
        int li = i * 256 + tid;
        int r = li >> 5, c2 = (li & 31) * 2;
        unsigned lo = t[c2][r], hi = t[c2 + 1][r];
        *(unsigned*)(vtb + (size_t)(e0 + r) * 512 + s0 + c2) = lo | (hi << 16);
    }
}

// ---------------------------------------------------------------------------
// K5a: fp32 scores (q.k*4, causal -1e24) + 2-pass softmax.
// Writes UNNORMALIZED exp(s-M) as bf16 P, plus 1/rowsum fp32.
__global__ __launch_bounds__(256, 2)
void score_kernel(const float* __restrict__ q, const float* __restrict__ k,
                  unsigned short* __restrict__ P, float* __restrict__ isum) {
    __shared__ float Kt[512 * 16];
    __shared__ float Qt[128 * 16];
    __shared__ float redm[2][128];
    __shared__ float reds[2][128];
    __shared__ unsigned short Pt[2][64][132];
    const int tid = threadIdx.x;
    const int b = blockIdx.y;
    const int t0 = blockIdx.x * 128;
    {
        const float4* ks = (const float4*)(k + (size_t)b * 512 * 16);
        float4* kd = (float4*)Kt;
#pragma unroll
        for (int i = 0; i < 8; i++) kd[i * 256 + tid] = ks[i * 256 + tid];
        const float4* qs = (const float4*)(q + ((size_t)b * 512 + t0) * 16);
        float4* qd = (float4*)Qt;
#pragma unroll
        for (int i = 0; i < 2; i++) qd[i * 256 + tid] = qs[i * 256 + tid];
    }
    __syncthreads();
    const int row = tid & 127;
    const int half = tid >> 7;
    const int sbeg = half * 256;
    const int tglob = t0 + row;
    float qr[16];
#pragma unroll
    for (int j = 0; j < 16; j++) qr[j] = Qt[row * 16 + j];

    float m = -INFINITY;
    for (int s = sbeg; s < sbeg + 256; s++) {
        const float* kk = Kt + s * 16;
        float dot = 0.f;
#pragma unroll
        for (int j = 0; j < 16; j++) dot = fmaf(qr[j], kk[j], dot);
        float sc = (s > tglob) ? NEG_BIG : dot * 4.0f;
        m = fmaxf(m, sc);
    }
    redm[half][row] = m;
    __syncthreads();
    const float M = fmaxf(redm[0][row], redm[1][row]);
    float sum = 0.f;
    for (int ph = 0; ph < 4; ph++) {
        const int c0 = sbeg + ph * 64;
        for (int s = c0; s < c0 + 64; s++) {
            const float* kk = Kt + s * 16;
            float dot = 0.f;
#pragma unroll
            for (int j = 0; j < 16; j++) dot = fmaf(qr[j], kk[j], dot);
            float sc = (s > tglob) ? NEG_BIG : dot * 4.0f;
            float p = __expf(sc - M);
            sum += p;
            Pt[half][s - c0][row] = f2bf(p);
        }
        __syncthreads();
#pragma unroll
        for (int i = 0; i < 8; i++) {
            int li = i * 256 + tid;
            int h = li >> 10;
            int r = (li >> 3) & 127;
            int cg = li & 7;
            union { unsigned short u[8]; uint4 v; } tmp;
#pragma unroll
            for (int j = 0; j < 8; j++) tmp.u[j] = Pt[h][cg * 8 + j][r];
            *(uint4*)(P + ((size_t)(b * 512 + t0 + r)) * 512 + h * 256 + ph * 64 + cg * 8) = tmp.v;
        }
        __syncthreads();
    }
    reds[half][row] = sum;
    __syncthreads();
    if (half == 0) {
        float tot = reds[0][row] + reds[1][row];
        isum[(size_t)b * 512 + tglob] = 1.0f / tot;
    }
}

// ---------------------------------------------------------------------------
// K5b: out[b][t][e] = (P[b] @ vT[b]^T)[t][e] * isum[b][t]   (full K=512!)
__global__ __launch_bounds__(256, 2)
void pv_kernel(const unsigned short* __restrict__ P,
               const unsigned short* __restrict__ vT,
               const float* __restrict__ isum,
               float* __restrict__ out) {
    __shared__ unsigned short As[128 * 32];
    __shared__ unsigned short Bs[128 * 32];
    const int tid = threadIdx.x;
    const int b = blockIdx.z;
    const int m0 = blockIdx.x * 128;
    const int n0 = blockIdx.y * 128;
    const int lane = tid & 63;
    const int wave = tid >> 6;
    const int wm = (wave & 1) * 64;
    const int wn = (wave >> 1) * 64;
    const int l15 = lane & 15;
    const int quad = lane >> 4;
    const int arow = tid >> 2;
    const int acol = (tid & 3) * 8;
    const unsigned short* Ab = P + (size_t)b * 512 * 512;
    const unsigned short* Bb = vT + (size_t)b * 1024 * 512;
    f32x4 acc[4][4];
#pragma unroll
    for (int i = 0; i < 4; i++)
#pragma unroll
        for (int j = 0; j < 4; j++)
#pragma unroll
            for (int r = 0; r < 4; r++) acc[i][j][r] = 0.f;

    for (int k0 = 0; k0 < 512; k0 += 32) {
        gload_lds16(Ab + (size_t)(m0 + arow) * 512 + k0 + acol, As + tid * 8);
        gload_lds16(Ab + (size_t)(m0 + 64 + arow) * 512 + k0 + acol, As + 2048 + tid * 8);
        gload_lds16(Bb + (size_t)(n0 + arow) * 512 + k0 + acol, Bs + tid * 8);
        gload_lds16(Bb + (size_t)(n0 + 64 + arow) * 512 + k0 + acol, Bs + 2048 + tid * 8);
        __syncthreads();
        bf16x8 af[4], bfr[4];
#pragma unroll
        for (int i = 0; i < 4; i++) {
            af[i]  = *(const bf16x8*)(As + (wm + i * 16 + l15) * 32 + quad * 8);
            bfr[i] = *(const bf16x8*)(Bs + (wn + i * 16 + l15) * 32 + quad * 8);
        }
#pragma unroll
        for (int i = 0; i < 4; i++)
#pragma unroll
            for (int j = 0; j < 4; j++)
                acc[i][j] = __builtin_amdgcn_mfma_f32_16x16x32_bf16(af[i], bfr[j], acc[i][j], 0, 0, 0);
        __syncthreads();
    }
#pragma unroll
    for (int i = 0; i < 4; i++) {
#pragma unroll
        for (int r = 0; r < 4; r++) {
            const int trow = m0 + wm + i * 16 + quad * 4 + r;
            const float sc = isum[(size_t)b * 512 + trow];
#pragma unroll
            for (int j = 0; j < 4; j++) {
                const int ncol = n0 + wn + j * 16 + l15;
                out[((size_t)b * 512 + trow) * 1024 + ncol] = acc[i][j][r] * sc;
            }
        }
    }
}

// ---------------------------------------------------------------------------
extern "C" void kernel_launch(void* const* d_in, const int* in_sizes, int n_in,
                              void* d_out, int out_size, void* d_ws, size_t ws_size,
                              hipStream_t stream) {
    const float* x  = (const float*)d_in[0];
    const void*  pm = d_in[1];
    const float* Wq = (const float*)d_in[2];
    const float* bq = (const float*)d_in[3];
    const float* Wk = (const float*)d_in[4];
    const float* bk = (const float*)d_in[5];
    const float* Wv = (const float*)d_in[6];
    const float* bv = (const float*)d_in[7];
    float* out = (float*)d_out;

    char* ws = (char*)d_ws;
    const size_t MB = 1024 * 1024;
    unsigned short* xbf = (unsigned short*)ws;                 // 64MB (K1->K3)
    unsigned short* Pun = (unsigned short*)ws;                 // 32MB overlay (K5a->K5b, after xbf dead)
    unsigned short* vT  = (unsigned short*)(ws + 64 * MB);     // 64MB
    float* qbuf = (float*)(ws + 128 * MB);                     // 2MB
    float* kbuf = (float*)(ws + 130 * MB);                     // 2MB
    unsigned short* WvT = (unsigned short*)(ws + 132 * MB);    // 2MB
    float* isum = (float*)(ws + 134 * MB);                     // 128KB
    int* flag   = (int*)(ws + 135 * MB);
    unsigned short* vnat = (unsigned short*)d_out;             // v bf16 scratch in d_out (overwritten by K5b)

    detect_mask_kernel<<<1, 256, 0, stream>>>((const unsigned*)pm, flag);
    qk_conv_kernel<<<512, 256, 0, stream>>>(x, Wq, bq, Wk, bk, pm, flag, xbf, qbuf, kbuf);
    wvt_kernel<<<dim3(32, 32), 256, 0, stream>>>(Wv, WvT);
    vgemm_kernel<<<dim3(256, 8), 256, 0, stream>>>(xbf, WvT, bv, vnat);
    transpose_v_kernel<<<dim3(8, 16, 64), 256, 0, stream>>>(vnat, vT);
    score_kernel<<<dim3(4, 64), 256, 0, stream>>>(qbuf, kbuf, Pun, isum);
    pv_kernel<<<dim3(4, 8, 64), 256, 0, stream>>>(Pun, vT, isum, out);
}